// Round 7
// baseline (356.288 us; speedup 1.0000x reference)
//
#include <hip/hip_runtime.h>
#include <hip/hip_bf16.h>

// Problem constants (BayesianLinear): IN_F=64, OUT_F=32, N=2080, B*S=16384
#define IN_F  64
#define OUT_F 32
#define NV    2080           // N
#define NPAD2 2304           // 18*128 rows (includes phantom bn=17, zeros)
#define MM    16384          // tokens
#define KK    2080           // contraction dim
#define NBN   17             // column tiles (output slabs)
#define NP    9              // bn-pairs: p<8 -> (2p,2p+1); p=8 -> (16, phantom)
#define NKT   65             // K tiles (KK/32)
#define BM    256            // row-tile = col-tile

typedef __attribute__((ext_vector_type(4))) float f32x4;
typedef __bf16 bf16x8 __attribute__((ext_vector_type(8)));

using gas_ptr = const __attribute__((address_space(1))) void*;
using lds_ptr = __attribute__((address_space(3))) void*;

// ---------------------------------------------------------------------------
// Kernel 1: build L (bf16, row-major [NPAD2][KK]); rows >= NV are zero.
// ---------------------------------------------------------------------------
__global__ __launch_bounds__(256) void build_L_k(const float* __restrict__ cov,
                                                 const float* __restrict__ logvar,
                                                 __hip_bfloat16* __restrict__ LB) {
    const int idx = blockIdx.x * 256 + threadIdx.x;   // over NPAD2*KK
    const int m = idx / KK;
    const int k = idx - m * KK;
    float v = 0.0f;
    if (m < NV) {
        if (k < m)       v = cov[(size_t)(m * (m - 1) / 2) + k];
        else if (k == m) v = expf(0.5f * logvar[m]);
    }
    LB[idx] = __float2bfloat16(v);
}

// ---------------------------------------------------------------------------
// Kernel 2 (v8): 256x256 tile, 512 threads (8 waves as 4 row x 2 col).
// Each wave = the verified 64x128 sub-kernel (acc[4][8], identical fragment
// offsets & epilogue); wave (wr,wc) serves column-block bnw = 2p+wc, so one
// A-staging feeds TWO bn columns (halves block-iters: 39K -> 22.6K, and
// halves the eps re-read).
//   A (eps fp32): global_load_lds, oct-swizzle o=(c&7)^(r&7) (v7-verified,
//     2-way = free).  In-reg fp32->bf16 cvt after ds_read.  NO prep kernel.
//   B (L bf16):   global_load_lds, part-swizzle (v2-verified).
//   Schedule = v2's proven distance-2: 3 buffers each, stage(t+2) pre-MFMA,
//     vmcnt(6) at the barrier keeps tile t+2's 6 ops (4A+2B per thread) in
//     flight; no lgkm drains in the loop.
//   LDS 152 KB -> 1 block/CU (2 waves/SIMD); pipeline depth replaces occupancy.
//   p=8: phantom bn=17 half is dead (act=false); L rows 2176..2303 are zeros.
//   Triangular: kmax = (p<8)? 8p+8 : 65; per-wave tail frag-skip
//     jlo = clamp(2t - 8*bnw, 0, 8)  (8 = wave fully dead this iter).
// ---------------------------------------------------------------------------
__global__ __launch_bounds__(512, 2) void gemm_v8_k(const float* __restrict__ A,
                                                    const __hip_bfloat16* __restrict__ BT,
                                                    const float* __restrict__ loc,
                                                    const float* __restrict__ x,
                                                    float* __restrict__ Ypart) {
    __shared__ __align__(16) float          As[3][BM * 32];   // 3 x 32 KB fp32
    __shared__ __align__(16) __hip_bfloat16 Bs[3][BM * 32];   // 3 x 16 KB bf16
    __shared__ float xs[BM][8];                               // 8 KB

    const int tid  = threadIdx.x;
    const int bm   = blockIdx.x;             // 0..63
    const int p    = (NP - 1) - blockIdx.y;  // heaviest pair (p=8) first
    const int wave = tid >> 6;
    const int lane = tid & 63;
    const int quad = lane >> 4;
    const int r16  = lane & 15;
    const int wr   = wave >> 1;              // 0..3 (row block)
    const int wc   = wave & 1;               // 0..1 (column half)
    const int bnw  = 2 * p + wc;             // this wave's bn (may be 17)
    const bool act = (bnw < NBN);
    const int kmax = (p < 8) ? (8 * p + 8) : NKT;

    // xs: weights for both halves.  Row = tid>>1; half pr = tid&1 covers
    // cc = 4pr..4pr+3: h = 8p + 4pr - 1 + c; bias (1.0) at p==0,pr==0,c==0.
    {
        const int rw = tid >> 1, pr = tid & 1;
        const int row = bm * BM + rw;
#pragma unroll
        for (int c = 0; c < 4; c++) {
            const int h = 8 * p + 4 * pr - 1 + c;
            float w = 0.0f;
            if (p == 0 && pr == 0 && c == 0)  w = 1.0f;
            else if (h >= 0 && h < IN_F)      w = x[(size_t)row * IN_F + h];
            xs[rw][4 * pr + c] = w;
        }
    }

    const float*          __restrict__ Ag = A  + (size_t)bm * BM * KK;       // fp32 eps
    const __hip_bfloat16* __restrict__ Bg = BT + (size_t)(BM * p) * KK;      // bf16 L rows 256p..

    // A staging map: 2048 chunks of 16B (4 fp32), 4/thread.
    // chunk c -> (row r=c>>3, slot s=c&7) holding oct o=s^(r&7); src r*KK+o*4.
    size_t agofs[4]; int aldso[4];
#pragma unroll
    for (int u = 0; u < 4; u++) {
        const int c = tid + 512 * u;
        const int r = c >> 3, o = (c & 7) ^ (r & 7);
        agofs[u] = (size_t)r * KK + (size_t)(o * 4);   // floats
        aldso[u] = c * 4;                              // float offset
    }
    // B staging map: 1024 chunks of 8 bf16, 2/thread; slot (c&3) holds part
    // (c&3)^((r>>1)&3)  (verified swizzle).
    size_t bgofs[2]; int bldso[2];
#pragma unroll
    for (int u = 0; u < 2; u++) {
        const int c = tid + 512 * u;
        const int r = c >> 2, pp = (c & 3) ^ ((r >> 1) & 3);
        bgofs[u] = (size_t)r * KK + (size_t)(pp * 8);  // bf16 elems
        bldso[u] = c * 8;
    }

    // fragment-read LDS offsets.  A (fp32, floats): frag i, octs {2q,2q+1}.
    int aof0[4], aof1[4];
#pragma unroll
    for (int i = 0; i < 4; i++) {
        const int row = 64 * wr + 16 * i + r16;
        aof0[i] = (row * 8 + ((2 * quad)     ^ (row & 7))) * 4;
        aof1[i] = (row * 8 + ((2 * quad + 1) ^ (row & 7))) * 4;
    }
    // B (bf16 elems): brow = 128*wc + 16j + r16 (verified formula).
    int bofs[8];
#pragma unroll
    for (int j = 0; j < 8; j++) {
        const int brow = 128 * wc + 16 * j + r16;
        bofs[j] = brow * 32 + (quad ^ ((brow >> 1) & 3)) * 8;
    }

    f32x4 acc[4][8];
#pragma unroll
    for (int i = 0; i < 4; i++)
#pragma unroll
        for (int j = 0; j < 8; j++) acc[i][j] = f32x4{0.f, 0.f, 0.f, 0.f};

    auto stage = [&](int t, int buf) __attribute__((always_inline)) {
        const float* ap = Ag + (size_t)t * 32;
#pragma unroll
        for (int u = 0; u < 4; u++)
            __builtin_amdgcn_global_load_lds((gas_ptr)(ap + agofs[u]),
                                             (lds_ptr)(&As[buf][0] + aldso[u]), 16, 0, 0);
        const __hip_bfloat16* bp = Bg + (size_t)t * 32;
#pragma unroll
        for (int u = 0; u < 2; u++)
            __builtin_amdgcn_global_load_lds((gas_ptr)(bp + bgofs[u]),
                                             (lds_ptr)(&Bs[buf][0] + bldso[u]), 16, 0, 0);
    };

    // --- prologue: tiles 0,1 in flight; wait tile 0 (vmcnt 6 = tile 1) ---
    stage(0, 0);
    stage(1, 1);
    __builtin_amdgcn_sched_barrier(0);
    asm volatile("s_waitcnt vmcnt(6)" ::: "memory");     // tile 0 landed
    asm volatile("s_waitcnt lgkmcnt(0)" ::: "memory");   // xs committed
    __builtin_amdgcn_s_barrier();
    __builtin_amdgcn_sched_barrier(0);

    // iter t: buf[t%3] ready for all waves; tile t+1 (6/thread) in flight.
    auto iter = [&](int t, int jlo) __attribute__((always_inline)) {
        const bool pf2 = (t + 2 < kmax);
        if (pf2) stage(t + 2, (t + 2) % 3);
        __builtin_amdgcn_sched_barrier(0);

        if (act && jlo < 8) {
            const float*          as = &As[t % 3][0];
            const __hip_bfloat16* bs = &Bs[t % 3][0];
            bf16x8 af[4];
#pragma unroll
            for (int i = 0; i < 4; i++) {
                const f32x4 x0 = *(const f32x4*)(as + aof0[i]);
                const f32x4 x1 = *(const f32x4*)(as + aof1[i]);
#pragma unroll
                for (int q = 0; q < 4; q++) {
                    af[i][q]     = (__bf16)x0[q];
                    af[i][4 + q] = (__bf16)x1[q];
                }
            }
            __builtin_amdgcn_s_setprio(1);
#pragma unroll
            for (int j = 0; j < 8; j++) {
                if (j >= jlo) {
                    const bf16x8 bfr = *(const bf16x8*)(bs + bofs[j]);
#pragma unroll
                    for (int i = 0; i < 4; i++)
                        acc[i][j] = __builtin_amdgcn_mfma_f32_16x16x32_bf16(af[i], bfr, acc[i][j], 0, 0, 0);
                }
            }
            __builtin_amdgcn_s_setprio(0);
        }

        if (t + 1 < kmax) {
            if (pf2) { asm volatile("s_waitcnt vmcnt(6)" ::: "memory"); }  // keep t+2
            else     { asm volatile("s_waitcnt vmcnt(0)" ::: "memory"); }
            __builtin_amdgcn_s_barrier();
            __builtin_amdgcn_sched_barrier(0);
        }
    };

    const int t_full = min(kmax, 8 * p + 1);   // both halves fully active
    int t = 0;
    for (; t < t_full; ++t) iter(t, 0);        // hot loop, branchless MFMAs
    for (; t < kmax; ++t) {                    // <=7 tail iters
        int jl = 2 * t - 8 * bnw;
        jl = jl < 0 ? 0 : (jl > 8 ? 8 : jl);
        iter(t, jl);
    }

    // per-wave epilogue (verified): C/D col=lane&15, row=quad*4+reg.
    if (act) {
        float locv[8];
#pragma unroll
        for (int j = 0; j < 8; j++) {
            const int col = bnw * 128 + 16 * j + r16;
            locv[j] = (col < NV) ? loc[col] : 0.0f;
        }
        float* yp = Ypart + ((size_t)bnw * MM + (size_t)bm * BM) * OUT_F;
#pragma unroll
        for (int i = 0; i < 4; i++) {
#pragma unroll
            for (int r = 0; r < 4; r++) {
                const int tl = 64 * wr + 16 * i + 4 * quad + r;
                float v0 = 0.0f, v1 = 0.0f;
#pragma unroll
                for (int c = 0; c < 4; c++) {
                    const float w = xs[tl][4 * wc + c];
                    v0 += w * (acc[i][2 * c][r]     + locv[2 * c]);
                    v1 += w * (acc[i][2 * c + 1][r] + locv[2 * c + 1]);
                }
                yp[(size_t)tl * OUT_F + r16]      = v0;
                yp[(size_t)tl * OUT_F + 16 + r16] = v1;
            }
        }
    }
}

// ---------------------------------------------------------------------------
// Kernel 3: reduce 17 partials -> y
// ---------------------------------------------------------------------------
__global__ __launch_bounds__(256) void reduce_y_k(const float4* __restrict__ yp,
                                                  float4* __restrict__ y) {
    const size_t i = (size_t)blockIdx.x * 256 + threadIdx.x;   // MM*32/4
    float4 s = yp[i];
#pragma unroll
    for (int b = 1; b < NBN; b++) {
        float4 v = yp[i + (size_t)b * (MM * OUT_F / 4)];
        s.x += v.x; s.y += v.y; s.z += v.z; s.w += v.w;
    }
    y[i] = s;
}

// ---------------------------------------------------------------------------
extern "C" void kernel_launch(void* const* d_in, const int* in_sizes, int n_in,
                              void* d_out, int out_size, void* d_ws, size_t ws_size,
                              hipStream_t stream) {
    const float* x      = (const float*)d_in[0];
    const float* eps    = (const float*)d_in[1];
    const float* loc    = (const float*)d_in[2];
    const float* logvar = (const float*)d_in[3];
    const float* cov    = (const float*)d_in[4];
    float* y = (float*)d_out;

    char* ws = (char*)d_ws;
    const size_t lb_bytes = (size_t)NPAD2 * KK * 2;           //  9.58 MB
    __hip_bfloat16* LB    = (__hip_bfloat16*)ws;
    float*          Ypart = (float*)(ws + lb_bytes);          // 17*MM*32*4 = 35.65 MB

    build_L_k<<<(NPAD2 * KK) / 256, 256, 0, stream>>>(cov, logvar, LB);
    gemm_v8_k<<<dim3(MM / BM, NP), 512, 0, stream>>>(eps, LB, loc, x, Ypart);
    reduce_y_k<<<(MM * OUT_F / 4) / 256, 256, 0, stream>>>((const float4*)Ypart, (float4*)y);
}